// Round 11
// baseline (829.515 us; speedup 1.0000x reference)
//
#include <hip/hip_runtime.h>
#include <hip/hip_bf16.h>

#define NNODES 50000
#define NEDGES 600000
#define NGRAPHS 128
#define EMB 128
#define NLAYERS 5
#define BN_EPS 1e-5f
#define NSB ((NNODES + 255) / 256)            // 196 node_S_bond blocks
#define EAB ((NNODES + 31) / 32)              // 1563 enc_atom blocks
#define BPB ((NLAYERS * 32768 + 255) / 256)   // 640 bprep blocks

typedef short s16x8 __attribute__((ext_vector_type(8)));
typedef float f32x16 __attribute__((ext_vector_type(16)));

__device__ __forceinline__ short f2bf(float f) {
    unsigned u = __builtin_bit_cast(unsigned, f);
    unsigned r = (u + 0x7fffu + ((u >> 16) & 1u)) >> 16;  // RNE
    return (short)r;
}
__device__ __forceinline__ float bf2f(short s) {
    return __builtin_bit_cast(float, ((unsigned)(unsigned short)s) << 16);
}

// ---------------- init: zero pool region, deg, stat (replaces 3 memsets) -----
__global__ __launch_bounds__(256) void init_kernel(float* __restrict__ pool,
                                                   int* __restrict__ deg,
                                                   float* __restrict__ stat) {
    int i = blockIdx.x * 256 + threadIdx.x;
    if (i < NGRAPHS * 640) pool[i] = 0.f;
    if (i < NNODES) deg[i] = 0;
    if (i < NLAYERS * 256) stat[i] = 0.f;
}

// ---------------- deg histogram (int atomics only) ---------------------------
__global__ __launch_bounds__(256) void deg_kernel(const int* __restrict__ ei,
                                                  int* __restrict__ deg) {
    int e = blockIdx.x * 256 + threadIdx.x;
    if (e >= NEDGES) return;
    atomicAdd(&deg[ei[NEDGES + e]], 1);
}

// ---------------- single-block scan (serial chunks + block scan) -------------
__global__ __launch_bounds__(1024) void scan_kernel(const int* __restrict__ deg,
                                                    int* __restrict__ rowptr,
                                                    int* __restrict__ cursor) {
    __shared__ int part[1024];
    int t = threadIdx.x;
    const int CHUNK = 49;  // 1024*49 = 50176 >= NNODES
    int begin = t * CHUNK;
    int end = begin + CHUNK;
    if (end > NNODES) end = NNODES;
    int s = 0;
    for (int i = begin; i < end; i++) s += deg[i];
    part[t] = s;
    __syncthreads();
    for (int off = 1; off < 1024; off <<= 1) {
        int v = (t >= off) ? part[t - off] : 0;
        __syncthreads();
        part[t] += v;
        __syncthreads();
    }
    int run = part[t] - s;
    for (int i = begin; i < end; i++) {
        rowptr[i] = run;
        cursor[i] = run;
        run += deg[i];
    }
    if (t == 1023) rowptr[NNODES] = part[1023];
}

// ---------------- fill CSR: 32B record {src, w, 11x bf16 attr, pad} ----------
__global__ __launch_bounds__(256) void edge_fill(const int* __restrict__ ei,
                                                 const float* __restrict__ ew,
                                                 const float* __restrict__ eattr,
                                                 int* __restrict__ cursor,
                                                 int* __restrict__ epk) {
    int e = blockIdx.x * 256 + threadIdx.x;
    if (e >= NEDGES) return;
    int src = ei[e];
    int dst = ei[NEDGES + e];
    int pos = atomicAdd(&cursor[dst], 1);
    int pk[8];
    pk[0] = src;
    pk[1] = __float_as_int(ew[e]);
    unsigned short a[12];
#pragma unroll
    for (int j = 0; j < 11; j++) a[j] = (unsigned short)f2bf(eattr[e * 11 + j]);
    a[11] = 0;
#pragma unroll
    for (int j = 0; j < 6; j++)
        pk[2 + j] = (int)a[2 * j] | ((int)a[2 * j + 1] << 16);
    int* dstp = epk + (size_t)pos * 8;
    *(int4*)dstp = *(int4*)pk;
    *(int4*)(dstp + 4) = *(int4*)(pk + 4);
}

// ---------------- prep2: heterogeneous {node_S+enc_bond | enc_atom | bprep} --
__global__ __launch_bounds__(256) void prep2(const int* __restrict__ rowptr,
                                             const int* __restrict__ epk,
                                             int2* __restrict__ epg,
                                             const float* __restrict__ Wb,
                                             const float* __restrict__ bbond,
                                             short* __restrict__ Ehi,
                                             const float* __restrict__ X,
                                             const float* __restrict__ Wa,
                                             const float* __restrict__ ba,
                                             short* __restrict__ Hhi,
                                             const float* __restrict__ Wl,
                                             const float* __restrict__ Wr,
                                             short* __restrict__ Bf) {
    __shared__ float shpool[1664];  // 6656 B, aliased by both branches
    int blk = blockIdx.x;
    int t = threadIdx.x;

    if (blk < NSB) {
        // ---- node_S + enc_bond fused: thread-per-node ----
        float* Wb_s = shpool;        // 11*128 = 1408
        float* bb_s = shpool + 1408; // 128
        for (int i = t; i < 1408; i += 256) Wb_s[i] = Wb[i];
        if (t < 128) bb_s[t] = bbond[t];
        __syncthreads();
        int node = blk * 256 + t;
        if (node >= NNODES) return;
        int b = rowptr[node], e = rowptr[node + 1];
        float s[11];
#pragma unroll
        for (int j = 0; j < 11; j++) s[j] = 0.f;
        float ws = 0.f;
        for (int p = b; p < e; p++) {
            const int* pk = epk + (size_t)p * 8;
            int4 lo = *(const int4*)pk;
            int4 hi = *(const int4*)(pk + 4);
            float w = __int_as_float(lo.y);
            ws += w;
            epg[p] = make_int2(lo.x, lo.y);   // compact {src,w} gather record
            int packed[6] = {lo.z, lo.w, hi.x, hi.y, hi.z, hi.w};
#pragma unroll
            for (int j = 0; j < 11; j++) {
                short v = (short)((packed[j >> 1] >> ((j & 1) * 16)) & 0xffff);
                s[j] += bf2f(v) * w;
            }
        }
        short* erow = Ehi + (size_t)node * 128;
#pragma unroll
        for (int c8 = 0; c8 < 16; c8++) {
            s16x8 o;
#pragma unroll
            for (int jj = 0; jj < 8; jj++) {
                int c = c8 * 8 + jj;
                float a = bb_s[c] * ws;
#pragma unroll
                for (int j = 0; j < 11; j++) a += s[j] * Wb_s[j * 128 + c];
                o[jj] = f2bf(a);
            }
            *(s16x8*)(erow + c8 * 8) = o;
        }
    } else if (blk < NSB + EAB) {
        // ---- enc_atom: h0 = x @ W_atom + b_atom -> bf16 ----
        float* as = shpool;  // 32*48 = 1536
        int row0 = (blk - NSB) * 32;
        for (int i = t; i < 32 * 48; i += 256) {
            int r = i / 48, c = i - r * 48;
            int gr = row0 + r;
            as[i] = (gr < NNODES) ? X[gr * 48 + c] : 0.f;
        }
        __syncthreads();
        int c = t & 127, rh = t >> 7;
        float acc[16];
#pragma unroll
        for (int i = 0; i < 16; i++) acc[i] = 0.f;
        for (int k = 0; k < 48; k++) {
            float w = Wa[k * 128 + c];
#pragma unroll
            for (int i = 0; i < 16; i++) acc[i] += as[(rh * 16 + i) * 48 + k] * w;
        }
        float bb = ba[c];
        for (int i = 0; i < 16; i++) {
            int gr = row0 + rh * 16 + i;
            if (gr < NNODES) Hhi[(size_t)gr * 128 + c] = f2bf(acc[i] + bb);
        }
    } else {
        // ---- bprep: weight fragments, hi/lo planes ----
        int idx = (blk - NSB - EAB) * 256 + t;
        if (idx >= NLAYERS * 32768) return;
        int layer = idx >> 15;
        int r = idx & 32767;
        int k = r >> 7, col = r & 127;
        float w = (k < 128) ? Wl[layer * 16384 + k * 128 + col]
                            : Wr[layer * 16384 + (k - 128) * 128 + col];
        short hi = f2bf(w);
        short lo = f2bf(w - bf2f(hi));
        int ks = k >> 4, half = (k >> 3) & 1, j = k & 7;
        int nt = col >> 5, n32 = col & 31;
        int fo = ((nt * 2 + half) * 32 + n32) * 8 + j;
        short* base = Bf + (size_t)layer * 65536 + ks * 4096;
        base[fo] = hi;
        base[2048 + fo] = lo;
    }
}

// ---------------- per-layer aggregation: bf16 gather -> Ahi plane ------------
__global__ __launch_bounds__(256) void agg_kernel(const short* __restrict__ Hhi,
                                                  const short* __restrict__ Ehi,
                                                  const int* __restrict__ rowptr,
                                                  const int2* __restrict__ epg,
                                                  short* __restrict__ Ahi) {
    int t = threadIdx.x;
    int lane = t & 31, grp = t >> 5;
    int c4 = lane * 4;
    int node = blockIdx.x * 8 + grp;
    if (node >= NNODES) return;
    int b = rowptr[node], e = rowptr[node + 1];
    float s0 = 0.f, s1 = 0.f, s2 = 0.f, s3 = 0.f;
    int p = b;
    for (; p + 1 < e; p += 2) {
        int2 pk0 = epg[p], pk1 = epg[p + 1];
        float w0 = __int_as_float(pk0.y), w1 = __int_as_float(pk1.y);
        ushort4 h0 = *(const ushort4*)&Hhi[(size_t)pk0.x * 128 + c4];
        ushort4 h1 = *(const ushort4*)&Hhi[(size_t)pk1.x * 128 + c4];
        s0 += bf2f((short)h0.x) * w0 + bf2f((short)h1.x) * w1;
        s1 += bf2f((short)h0.y) * w0 + bf2f((short)h1.y) * w1;
        s2 += bf2f((short)h0.z) * w0 + bf2f((short)h1.z) * w1;
        s3 += bf2f((short)h0.w) * w0 + bf2f((short)h1.w) * w1;
    }
    if (p < e) {
        int2 pk0 = epg[p];
        float w0 = __int_as_float(pk0.y);
        ushort4 h0 = *(const ushort4*)&Hhi[(size_t)pk0.x * 128 + c4];
        s0 += bf2f((short)h0.x) * w0;
        s1 += bf2f((short)h0.y) * w0;
        s2 += bf2f((short)h0.z) * w0;
        s3 += bf2f((short)h0.w) * w0;
    }
    float inv = 1.f / fmaxf((float)(e - b), 1.f);
    ushort4 ea = *(const ushort4*)&Ehi[(size_t)node * 128 + c4];
    ushort4 o;
    o.x = (unsigned short)f2bf((s0 + bf2f((short)ea.x)) * inv);
    o.y = (unsigned short)f2bf((s1 + bf2f((short)ea.y)) * inv);
    o.z = (unsigned short)f2bf((s2 + bf2f((short)ea.z)) * inv);
    o.w = (unsigned short)f2bf((s3 + bf2f((short)ea.w)) * inv);
    *(ushort4*)&Ahi[(size_t)node * 128 + c4] = o;
}

// ---------------- MFMA GEMM (32x32x16, A hi-only, 2-way K-split) -------------
// Block = 64 rows, 4 waves: wave(tile = w&1, khalf = w>>1). Each wave: 8 ksteps.
// khalf=1 partials via conflict-free LDS; khalf=0 combines + epilogue.
__global__ __launch_bounds__(256) void layer_gemm(const short* __restrict__ Ahi,
                                                  const short* __restrict__ Hhi,
                                                  const short* __restrict__ Bf,
                                                  const float* __restrict__ bias,
                                                  short* __restrict__ Cbf,
                                                  float* __restrict__ stat) {
    __shared__ float red[2][4096];
    __shared__ float s_s[128], s_q[128];
    int t = threadIdx.x;
    int wave = t >> 6, lane = t & 63;
    int n32 = lane & 31, half = lane >> 5;
    int tile = wave & 1, khalf = wave >> 1;
    int row0 = blockIdx.x * 64 + tile * 32;

    if (t < 128) { s_s[t] = 0.f; s_q[t] = 0.f; }

    int myrow = row0 + n32;
    bool rowok = myrow < NNODES;
    size_t rbase = (size_t)myrow * 128;
    int acol = half * 8;
    const short* Asrc = khalf ? Hhi : Ahi;

    f32x16 acc[4];
#pragma unroll
    for (int i = 0; i < 4; i++) acc[i] = (f32x16)(0.f);

    const short* bb0 = Bf + khalf * 8 * 4096 + half * 256 + n32 * 8;

    s16x8 ah = {0, 0, 0, 0, 0, 0, 0, 0};
    s16x8 bh[4], bl[4];
    if (rowok) ah = *(const s16x8*)(Asrc + rbase + acol);
#pragma unroll
    for (int nt = 0; nt < 4; nt++) {
        bh[nt] = *(const s16x8*)(bb0 + nt * 512);
        bl[nt] = *(const s16x8*)(bb0 + 2048 + nt * 512);
    }

#pragma unroll
    for (int ks = 0; ks < 8; ks++) {
        s16x8 ah2 = {0, 0, 0, 0, 0, 0, 0, 0};
        s16x8 bh2[4], bl2[4];
        if (ks < 7) {
            int kn = ks + 1;
            if (rowok) ah2 = *(const s16x8*)(Asrc + rbase + kn * 16 + acol);
            const short* bbn = bb0 + kn * 4096;
#pragma unroll
            for (int nt = 0; nt < 4; nt++) {
                bh2[nt] = *(const s16x8*)(bbn + nt * 512);
                bl2[nt] = *(const s16x8*)(bbn + 2048 + nt * 512);
            }
        }
#pragma unroll
        for (int nt = 0; nt < 4; nt++) {
            acc[nt] = __builtin_amdgcn_mfma_f32_32x32x16_bf16(ah, bh[nt], acc[nt], 0, 0, 0);
            acc[nt] = __builtin_amdgcn_mfma_f32_32x32x16_bf16(ah, bl[nt], acc[nt], 0, 0, 0);
        }
        if (ks < 7) {
            ah = ah2;
#pragma unroll
            for (int nt = 0; nt < 4; nt++) {
                bh[nt] = bh2[nt];
                bl[nt] = bl2[nt];
            }
        }
    }

    if (khalf == 1) {
#pragma unroll
        for (int nt = 0; nt < 4; nt++)
#pragma unroll
            for (int reg = 0; reg < 16; reg++)
                red[tile][(nt * 16 + reg) * 64 + lane] = acc[nt][reg];
    }
    __syncthreads();
    if (khalf == 0) {
#pragma unroll
        for (int nt = 0; nt < 4; nt++) {
            int col = nt * 32 + n32;
            float bb = bias[col];
            float ss = 0.f, qq = 0.f;
#pragma unroll
            for (int reg = 0; reg < 16; reg++) {
                int r = row0 + (reg & 3) + 8 * (reg >> 2) + 4 * half;
                if (r < NNODES) {
                    float v = acc[nt][reg] + red[tile][(nt * 16 + reg) * 64 + lane] + bb;
                    Cbf[(size_t)r * 128 + col] = f2bf(v);
                    ss += v;
                    qq += v * v;
                }
            }
            ss += __shfl_xor(ss, 32);
            qq += __shfl_xor(qq, 32);
            if (half == 0) {
                atomicAdd(&s_s[col], ss);
                atomicAdd(&s_q[col], qq);
            }
        }
    }
    __syncthreads();
    if (t < 128) {
        atomicAdd(&stat[t], s_s[t]);
        atomicAdd(&stat[128 + t], s_q[t]);
    }
}

// ---------------- BN apply (+inline coef) + ReLU + xpool ---------------------
__global__ __launch_bounds__(256) void bn_apply(const short* __restrict__ Cbf,
                                                short* __restrict__ Hhi,
                                                float* __restrict__ Hf32,
                                                const float* __restrict__ stat,
                                                const float* __restrict__ gamma,
                                                const float* __restrict__ beta,
                                                const int* __restrict__ batch,
                                                float* __restrict__ pool,
                                                int layer, int relu) {
    __shared__ float csc[128], csh[128];
    int t = threadIdx.x;
    if (t < 128) {
        const float invM = 1.f / (float)NNODES;
        float mu = stat[t] * invM;
        float var = stat[128 + t] * invM - mu * mu;
        float inv = rsqrtf(var + BN_EPS);
        float sc = gamma[t] * inv;
        csc[t] = sc;
        csh[t] = beta[t] - mu * sc;
    }
    __syncthreads();
    int lane = t & 31, grp = t >> 5;
    int c4 = lane * 4;
    float4 sc = *(const float4*)&csc[c4];
    float4 sh = *(const float4*)&csh[c4];
    int row0 = blockIdx.x * 256;
    float4 accp = {0.f, 0.f, 0.f, 0.f};
    int curg = -1;
    float* pbase = pool + layer * 128 + c4;
    for (int rr = grp; rr < 256; rr += 8) {
        int r = row0 + rr;
        if (r >= NNODES) break;
        ushort4 cv = *(const ushort4*)&Cbf[(size_t)r * 128 + c4];
        float4 v;
        v.x = bf2f((short)cv.x) * sc.x + sh.x;
        v.y = bf2f((short)cv.y) * sc.y + sh.y;
        v.z = bf2f((short)cv.z) * sc.z + sh.z;
        v.w = bf2f((short)cv.w) * sc.w + sh.w;
        if (relu) {
            v.x = fmaxf(v.x, 0.f);
            v.y = fmaxf(v.y, 0.f);
            v.z = fmaxf(v.z, 0.f);
            v.w = fmaxf(v.w, 0.f);
        }
        if (Hf32) {
            *(float4*)&Hf32[(size_t)r * 128 + c4] = v;
        } else {
            ushort4 hv;
            hv.x = (unsigned short)f2bf(v.x);
            hv.y = (unsigned short)f2bf(v.y);
            hv.z = (unsigned short)f2bf(v.z);
            hv.w = (unsigned short)f2bf(v.w);
            *(ushort4*)&Hhi[(size_t)r * 128 + c4] = hv;
        }
        int g = batch[r];
        if (g != curg) {
            if (curg >= 0) {
                float* p = pbase + curg * 640;
                atomicAdd(p + 0, accp.x);
                atomicAdd(p + 1, accp.y);
                atomicAdd(p + 2, accp.z);
                atomicAdd(p + 3, accp.w);
            }
            curg = g;
            accp.x = accp.y = accp.z = accp.w = 0.f;
        }
        accp.x += v.x;
        accp.y += v.y;
        accp.z += v.z;
        accp.w += v.w;
    }
    if (curg >= 0) {
        float* p = pbase + curg * 640;
        atomicAdd(p + 0, accp.x);
        atomicAdd(p + 1, accp.y);
        atomicAdd(p + 2, accp.z);
        atomicAdd(p + 3, accp.w);
    }
}

extern "C" void kernel_launch(void* const* d_in, const int* in_sizes, int n_in,
                              void* d_out, int out_size, void* d_ws, size_t ws_size,
                              hipStream_t stream) {
    const int* batch = (const int*)d_in[0];
    const float* x = (const float*)d_in[1];
    const int* edge_index = (const int*)d_in[2];
    const float* edge_attr = (const float*)d_in[3];
    const float* edge_weight = (const float*)d_in[4];
    const float* W_atom = (const float*)d_in[5];
    const float* b_atom = (const float*)d_in[6];
    const float* W_bond = (const float*)d_in[7];
    const float* b_bond = (const float*)d_in[8];
    const float* Wl = (const float*)d_in[9];
    const float* bl = (const float*)d_in[10];
    const float* Wr = (const float*)d_in[11];
    const float* gamma = (const float*)d_in[12];
    const float* beta = (const float*)d_in[13];
    float* out = (float*)d_out;

    // ---- workspace layout ----
    char* ws = (char*)d_ws;
    size_t off = 0;
    auto alloc = [&](size_t bytes) -> void* {
        void* p = ws + off;
        off += (bytes + 255) & ~(size_t)255;
        return p;
    };
    short* Hhi = (short*)alloc((size_t)NNODES * 128 * 2);
    short* Ahi = (short*)alloc((size_t)NNODES * 128 * 2);
    short* Cbf = (short*)alloc((size_t)NNODES * 128 * 2);
    short* Ehi = (short*)alloc((size_t)NNODES * 128 * 2);
    int* epk = (int*)alloc((size_t)NEDGES * 32);
    int2* epg = (int2*)alloc((size_t)NEDGES * 8);
    int* rowptr = (int*)alloc((size_t)(NNODES + 1) * 4);
    int* cursor = (int*)alloc((size_t)NNODES * 4);
    int* deg = (int*)alloc((size_t)NNODES * 4);
    float* stat = (float*)alloc(NLAYERS * 256 * 4);
    short* Bf = (short*)alloc((size_t)NLAYERS * 65536 * 2);

    // ---- preprocessing (20 dispatches total incl. layers) ----
    init_kernel<<<(NGRAPHS * 640 + 255) / 256, 256, 0, stream>>>(out, deg, stat);
    deg_kernel<<<(NEDGES + 255) / 256, 256, 0, stream>>>(edge_index, deg);
    scan_kernel<<<1, 1024, 0, stream>>>(deg, rowptr, cursor);
    edge_fill<<<(NEDGES + 255) / 256, 256, 0, stream>>>(edge_index, edge_weight,
                                                        edge_attr, cursor, epk);
    prep2<<<NSB + EAB + BPB, 256, 0, stream>>>(rowptr, epk, epg, W_bond, b_bond, Ehi,
                                               x, W_atom, b_atom, Hhi, Wl, Wr, Bf);

    // ---- layers ----
    for (int i = 0; i < NLAYERS; i++) {
        agg_kernel<<<(NNODES + 7) / 8, 256, 0, stream>>>(Hhi, Ehi, rowptr, epg, Ahi);
        layer_gemm<<<(NNODES + 63) / 64, 256, 0, stream>>>(Ahi, Hhi,
                                                           Bf + (size_t)i * 65536,
                                                           bl + i * 128, Cbf,
                                                           stat + i * 256);
        int last = (i == NLAYERS - 1);
        bn_apply<<<(NNODES + 255) / 256, 256, 0, stream>>>(
            Cbf, Hhi, last ? (out + (size_t)NGRAPHS * 640) : nullptr,
            stat + i * 256, gamma + i * 128, beta + i * 128, batch, out, i,
            last ? 0 : 1);
    }
}

// Round 12
// 735.376 us; speedup vs baseline: 1.1280x; 1.1280x over previous
//
#include <hip/hip_runtime.h>
#include <hip/hip_bf16.h>

#define NNODES 50000
#define NEDGES 600000
#define NGRAPHS 128
#define EMB 128
#define NLAYERS 5
#define BN_EPS 1e-5f
#define SCAN_BLOCKS ((NNODES + 255) / 256)    // 196
#define NSB ((NNODES + 255) / 256)            // 196 node_S_bond blocks
#define EAB ((NNODES + 31) / 32)              // 1563 enc_atom blocks
#define BPB ((NLAYERS * 32768 + 255) / 256)   // 640 bprep blocks

typedef short s16x8 __attribute__((ext_vector_type(8)));
typedef float f32x16 __attribute__((ext_vector_type(16)));

__device__ __forceinline__ short f2bf(float f) {
    unsigned u = __builtin_bit_cast(unsigned, f);
    unsigned r = (u + 0x7fffu + ((u >> 16) & 1u)) >> 16;  // RNE
    return (short)r;
}
__device__ __forceinline__ float bf2f(short s) {
    return __builtin_bit_cast(float, ((unsigned)(unsigned short)s) << 16);
}

// ---------------- init: zero pool region, deg, stat (replaces 3 memsets) -----
__global__ __launch_bounds__(256) void init_kernel(float* __restrict__ pool,
                                                   int* __restrict__ deg,
                                                   float* __restrict__ stat) {
    int i = blockIdx.x * 256 + threadIdx.x;
    if (i < NGRAPHS * 640) pool[i] = 0.f;
    if (i < NNODES) deg[i] = 0;
    if (i < NLAYERS * 256) stat[i] = 0.f;
}

// ---------------- deg histogram (int atomics only) ---------------------------
__global__ __launch_bounds__(256) void deg_kernel(const int* __restrict__ ei,
                                                  int* __restrict__ deg) {
    int e = blockIdx.x * 256 + threadIdx.x;
    if (e >= NEDGES) return;
    atomicAdd(&deg[ei[NEDGES + e]], 1);
}

// ---------------- multi-block scan (restored from r10: 3 fast dispatches) ----
__global__ __launch_bounds__(256) void scan1(const int* __restrict__ deg,
                                             int* __restrict__ local_excl,
                                             int* __restrict__ part) {
    __shared__ int sh[256];
    int t = threadIdx.x;
    int i = blockIdx.x * 256 + t;
    int v = (i < NNODES) ? deg[i] : 0;
    sh[t] = v;
    __syncthreads();
    for (int off = 1; off < 256; off <<= 1) {
        int u = (t >= off) ? sh[t - off] : 0;
        __syncthreads();
        sh[t] += u;
        __syncthreads();
    }
    if (i < NNODES) local_excl[i] = sh[t] - v;
    if (t == 255) part[blockIdx.x] = sh[255];
}

__global__ __launch_bounds__(256) void scan2(int* __restrict__ part,
                                             int* __restrict__ blockoff,
                                             int* __restrict__ rowptr) {
    __shared__ int sh[256];
    int t = threadIdx.x;
    int v = (t < SCAN_BLOCKS) ? part[t] : 0;
    sh[t] = v;
    __syncthreads();
    for (int off = 1; off < 256; off <<= 1) {
        int u = (t >= off) ? sh[t - off] : 0;
        __syncthreads();
        sh[t] += u;
        __syncthreads();
    }
    if (t < SCAN_BLOCKS) blockoff[t] = sh[t] - v;
    if (t == 255) rowptr[NNODES] = sh[255];
}

__global__ __launch_bounds__(256) void scan3(const int* __restrict__ local_excl,
                                             const int* __restrict__ blockoff,
                                             int* __restrict__ rowptr,
                                             int* __restrict__ cursor) {
    int i = blockIdx.x * 256 + threadIdx.x;
    if (i >= NNODES) return;
    int v = local_excl[i] + blockoff[blockIdx.x];
    rowptr[i] = v;
    cursor[i] = v;
}

// ---------------- fill CSR: 32B record {src, w, 11x bf16 attr, pad} ----------
__global__ __launch_bounds__(256) void edge_fill(const int* __restrict__ ei,
                                                 const float* __restrict__ ew,
                                                 const float* __restrict__ eattr,
                                                 int* __restrict__ cursor,
                                                 int* __restrict__ epk) {
    int e = blockIdx.x * 256 + threadIdx.x;
    if (e >= NEDGES) return;
    int src = ei[e];
    int dst = ei[NEDGES + e];
    int pos = atomicAdd(&cursor[dst], 1);
    int pk[8];
    pk[0] = src;
    pk[1] = __float_as_int(ew[e]);
    unsigned short a[12];
#pragma unroll
    for (int j = 0; j < 11; j++) a[j] = (unsigned short)f2bf(eattr[e * 11 + j]);
    a[11] = 0;
#pragma unroll
    for (int j = 0; j < 6; j++)
        pk[2 + j] = (int)a[2 * j] | ((int)a[2 * j + 1] << 16);
    int* dstp = epk + (size_t)pos * 8;
    *(int4*)dstp = *(int4*)pk;
    *(int4*)(dstp + 4) = *(int4*)(pk + 4);
}

// ---------------- prep2: heterogeneous {node_S+enc_bond | enc_atom | bprep} --
__global__ __launch_bounds__(256) void prep2(const int* __restrict__ rowptr,
                                             const int* __restrict__ epk,
                                             int2* __restrict__ epg,
                                             const float* __restrict__ Wb,
                                             const float* __restrict__ bbond,
                                             short* __restrict__ Ehi,
                                             const float* __restrict__ X,
                                             const float* __restrict__ Wa,
                                             const float* __restrict__ ba,
                                             short* __restrict__ Hhi,
                                             const float* __restrict__ Wl,
                                             const float* __restrict__ Wr,
                                             short* __restrict__ Bf) {
    __shared__ float shpool[1664];  // 6656 B, aliased by both branches
    int blk = blockIdx.x;
    int t = threadIdx.x;

    if (blk < NSB) {
        // ---- node_S + enc_bond fused: thread-per-node ----
        float* Wb_s = shpool;        // 11*128 = 1408
        float* bb_s = shpool + 1408; // 128
        for (int i = t; i < 1408; i += 256) Wb_s[i] = Wb[i];
        if (t < 128) bb_s[t] = bbond[t];
        __syncthreads();
        int node = blk * 256 + t;
        if (node >= NNODES) return;
        int b = rowptr[node], e = rowptr[node + 1];
        float s[11];
#pragma unroll
        for (int j = 0; j < 11; j++) s[j] = 0.f;
        float ws = 0.f;
        for (int p = b; p < e; p++) {
            const int* pk = epk + (size_t)p * 8;
            int4 lo = *(const int4*)pk;
            int4 hi = *(const int4*)(pk + 4);
            float w = __int_as_float(lo.y);
            ws += w;
            epg[p] = make_int2(lo.x, lo.y);   // compact {src,w} gather record
            int packed[6] = {lo.z, lo.w, hi.x, hi.y, hi.z, hi.w};
#pragma unroll
            for (int j = 0; j < 11; j++) {
                short v = (short)((packed[j >> 1] >> ((j & 1) * 16)) & 0xffff);
                s[j] += bf2f(v) * w;
            }
        }
        short* erow = Ehi + (size_t)node * 128;
#pragma unroll
        for (int c8 = 0; c8 < 16; c8++) {
            s16x8 o;
#pragma unroll
            for (int jj = 0; jj < 8; jj++) {
                int c = c8 * 8 + jj;
                float a = bb_s[c] * ws;
#pragma unroll
                for (int j = 0; j < 11; j++) a += s[j] * Wb_s[j * 128 + c];
                o[jj] = f2bf(a);
            }
            *(s16x8*)(erow + c8 * 8) = o;
        }
    } else if (blk < NSB + EAB) {
        // ---- enc_atom: h0 = x @ W_atom + b_atom -> bf16 ----
        float* as = shpool;  // 32*48 = 1536
        int row0 = (blk - NSB) * 32;
        for (int i = t; i < 32 * 48; i += 256) {
            int r = i / 48, c = i - r * 48;
            int gr = row0 + r;
            as[i] = (gr < NNODES) ? X[gr * 48 + c] : 0.f;
        }
        __syncthreads();
        int c = t & 127, rh = t >> 7;
        float acc[16];
#pragma unroll
        for (int i = 0; i < 16; i++) acc[i] = 0.f;
        for (int k = 0; k < 48; k++) {
            float w = Wa[k * 128 + c];
#pragma unroll
            for (int i = 0; i < 16; i++) acc[i] += as[(rh * 16 + i) * 48 + k] * w;
        }
        float bb = ba[c];
        for (int i = 0; i < 16; i++) {
            int gr = row0 + rh * 16 + i;
            if (gr < NNODES) Hhi[(size_t)gr * 128 + c] = f2bf(acc[i] + bb);
        }
    } else {
        // ---- bprep: weight fragments, hi/lo planes ----
        int idx = (blk - NSB - EAB) * 256 + t;
        if (idx >= NLAYERS * 32768) return;
        int layer = idx >> 15;
        int r = idx & 32767;
        int k = r >> 7, col = r & 127;
        float w = (k < 128) ? Wl[layer * 16384 + k * 128 + col]
                            : Wr[layer * 16384 + (k - 128) * 128 + col];
        short hi = f2bf(w);
        short lo = f2bf(w - bf2f(hi));
        int ks = k >> 4, half = (k >> 3) & 1, j = k & 7;
        int nt = col >> 5, n32 = col & 31;
        int fo = ((nt * 2 + half) * 32 + n32) * 8 + j;
        short* base = Bf + (size_t)layer * 65536 + ks * 4096;
        base[fo] = hi;
        base[2048 + fo] = lo;
    }
}

// ---------------- per-layer aggregation: bf16 gather -> Ahi plane ------------
__global__ __launch_bounds__(256) void agg_kernel(const short* __restrict__ Hhi,
                                                  const short* __restrict__ Ehi,
                                                  const int* __restrict__ rowptr,
                                                  const int2* __restrict__ epg,
                                                  short* __restrict__ Ahi) {
    int t = threadIdx.x;
    int lane = t & 31, grp = t >> 5;
    int c4 = lane * 4;
    int node = blockIdx.x * 8 + grp;
    if (node >= NNODES) return;
    int b = rowptr[node], e = rowptr[node + 1];
    float s0 = 0.f, s1 = 0.f, s2 = 0.f, s3 = 0.f;
    int p = b;
    for (; p + 1 < e; p += 2) {
        int2 pk0 = epg[p], pk1 = epg[p + 1];
        float w0 = __int_as_float(pk0.y), w1 = __int_as_float(pk1.y);
        ushort4 h0 = *(const ushort4*)&Hhi[(size_t)pk0.x * 128 + c4];
        ushort4 h1 = *(const ushort4*)&Hhi[(size_t)pk1.x * 128 + c4];
        s0 += bf2f((short)h0.x) * w0 + bf2f((short)h1.x) * w1;
        s1 += bf2f((short)h0.y) * w0 + bf2f((short)h1.y) * w1;
        s2 += bf2f((short)h0.z) * w0 + bf2f((short)h1.z) * w1;
        s3 += bf2f((short)h0.w) * w0 + bf2f((short)h1.w) * w1;
    }
    if (p < e) {
        int2 pk0 = epg[p];
        float w0 = __int_as_float(pk0.y);
        ushort4 h0 = *(const ushort4*)&Hhi[(size_t)pk0.x * 128 + c4];
        s0 += bf2f((short)h0.x) * w0;
        s1 += bf2f((short)h0.y) * w0;
        s2 += bf2f((short)h0.z) * w0;
        s3 += bf2f((short)h0.w) * w0;
    }
    float inv = 1.f / fmaxf((float)(e - b), 1.f);
    ushort4 ea = *(const ushort4*)&Ehi[(size_t)node * 128 + c4];
    ushort4 o;
    o.x = (unsigned short)f2bf((s0 + bf2f((short)ea.x)) * inv);
    o.y = (unsigned short)f2bf((s1 + bf2f((short)ea.y)) * inv);
    o.z = (unsigned short)f2bf((s2 + bf2f((short)ea.z)) * inv);
    o.w = (unsigned short)f2bf((s3 + bf2f((short)ea.w)) * inv);
    *(ushort4*)&Ahi[(size_t)node * 128 + c4] = o;
}

// ---------------- MFMA GEMM (32x32x16, A hi-only, 2-way K-split) -------------
__global__ __launch_bounds__(256) void layer_gemm(const short* __restrict__ Ahi,
                                                  const short* __restrict__ Hhi,
                                                  const short* __restrict__ Bf,
                                                  const float* __restrict__ bias,
                                                  short* __restrict__ Cbf,
                                                  float* __restrict__ stat) {
    __shared__ float red[2][4096];
    __shared__ float s_s[128], s_q[128];
    int t = threadIdx.x;
    int wave = t >> 6, lane = t & 63;
    int n32 = lane & 31, half = lane >> 5;
    int tile = wave & 1, khalf = wave >> 1;
    int row0 = blockIdx.x * 64 + tile * 32;

    if (t < 128) { s_s[t] = 0.f; s_q[t] = 0.f; }

    int myrow = row0 + n32;
    bool rowok = myrow < NNODES;
    size_t rbase = (size_t)myrow * 128;
    int acol = half * 8;
    const short* Asrc = khalf ? Hhi : Ahi;

    f32x16 acc[4];
#pragma unroll
    for (int i = 0; i < 4; i++) acc[i] = (f32x16)(0.f);

    const short* bb0 = Bf + khalf * 8 * 4096 + half * 256 + n32 * 8;

    s16x8 ah = {0, 0, 0, 0, 0, 0, 0, 0};
    s16x8 bh[4], bl[4];
    if (rowok) ah = *(const s16x8*)(Asrc + rbase + acol);
#pragma unroll
    for (int nt = 0; nt < 4; nt++) {
        bh[nt] = *(const s16x8*)(bb0 + nt * 512);
        bl[nt] = *(const s16x8*)(bb0 + 2048 + nt * 512);
    }

#pragma unroll
    for (int ks = 0; ks < 8; ks++) {
        s16x8 ah2 = {0, 0, 0, 0, 0, 0, 0, 0};
        s16x8 bh2[4], bl2[4];
        if (ks < 7) {
            int kn = ks + 1;
            if (rowok) ah2 = *(const s16x8*)(Asrc + rbase + kn * 16 + acol);
            const short* bbn = bb0 + kn * 4096;
#pragma unroll
            for (int nt = 0; nt < 4; nt++) {
                bh2[nt] = *(const s16x8*)(bbn + nt * 512);
                bl2[nt] = *(const s16x8*)(bbn + 2048 + nt * 512);
            }
        }
#pragma unroll
        for (int nt = 0; nt < 4; nt++) {
            acc[nt] = __builtin_amdgcn_mfma_f32_32x32x16_bf16(ah, bh[nt], acc[nt], 0, 0, 0);
            acc[nt] = __builtin_amdgcn_mfma_f32_32x32x16_bf16(ah, bl[nt], acc[nt], 0, 0, 0);
        }
        if (ks < 7) {
            ah = ah2;
#pragma unroll
            for (int nt = 0; nt < 4; nt++) {
                bh[nt] = bh2[nt];
                bl[nt] = bl2[nt];
            }
        }
    }

    if (khalf == 1) {
#pragma unroll
        for (int nt = 0; nt < 4; nt++)
#pragma unroll
            for (int reg = 0; reg < 16; reg++)
                red[tile][(nt * 16 + reg) * 64 + lane] = acc[nt][reg];
    }
    __syncthreads();
    if (khalf == 0) {
#pragma unroll
        for (int nt = 0; nt < 4; nt++) {
            int col = nt * 32 + n32;
            float bb = bias[col];
            float ss = 0.f, qq = 0.f;
#pragma unroll
            for (int reg = 0; reg < 16; reg++) {
                int r = row0 + (reg & 3) + 8 * (reg >> 2) + 4 * half;
                if (r < NNODES) {
                    float v = acc[nt][reg] + red[tile][(nt * 16 + reg) * 64 + lane] + bb;
                    Cbf[(size_t)r * 128 + col] = f2bf(v);
                    ss += v;
                    qq += v * v;
                }
            }
            ss += __shfl_xor(ss, 32);
            qq += __shfl_xor(qq, 32);
            if (half == 0) {
                atomicAdd(&s_s[col], ss);
                atomicAdd(&s_q[col], qq);
            }
        }
    }
    __syncthreads();
    if (t < 128) {
        atomicAdd(&stat[t], s_s[t]);
        atomicAdd(&stat[128 + t], s_q[t]);
    }
}

// ---------------- BN apply (+inline coef) + ReLU + xpool ---------------------
__global__ __launch_bounds__(256) void bn_apply(const short* __restrict__ Cbf,
                                                short* __restrict__ Hhi,
                                                float* __restrict__ Hf32,
                                                const float* __restrict__ stat,
                                                const float* __restrict__ gamma,
                                                const float* __restrict__ beta,
                                                const int* __restrict__ batch,
                                                float* __restrict__ pool,
                                                int layer, int relu) {
    __shared__ float csc[128], csh[128];
    int t = threadIdx.x;
    if (t < 128) {
        const float invM = 1.f / (float)NNODES;
        float mu = stat[t] * invM;
        float var = stat[128 + t] * invM - mu * mu;
        float inv = rsqrtf(var + BN_EPS);
        float sc = gamma[t] * inv;
        csc[t] = sc;
        csh[t] = beta[t] - mu * sc;
    }
    __syncthreads();
    int lane = t & 31, grp = t >> 5;
    int c4 = lane * 4;
    float4 sc = *(const float4*)&csc[c4];
    float4 sh = *(const float4*)&csh[c4];
    int row0 = blockIdx.x * 256;
    float4 accp = {0.f, 0.f, 0.f, 0.f};
    int curg = -1;
    float* pbase = pool + layer * 128 + c4;
    for (int rr = grp; rr < 256; rr += 8) {
        int r = row0 + rr;
        if (r >= NNODES) break;
        ushort4 cv = *(const ushort4*)&Cbf[(size_t)r * 128 + c4];
        float4 v;
        v.x = bf2f((short)cv.x) * sc.x + sh.x;
        v.y = bf2f((short)cv.y) * sc.y + sh.y;
        v.z = bf2f((short)cv.z) * sc.z + sh.z;
        v.w = bf2f((short)cv.w) * sc.w + sh.w;
        if (relu) {
            v.x = fmaxf(v.x, 0.f);
            v.y = fmaxf(v.y, 0.f);
            v.z = fmaxf(v.z, 0.f);
            v.w = fmaxf(v.w, 0.f);
        }
        if (Hf32) {
            *(float4*)&Hf32[(size_t)r * 128 + c4] = v;
        } else {
            ushort4 hv;
            hv.x = (unsigned short)f2bf(v.x);
            hv.y = (unsigned short)f2bf(v.y);
            hv.z = (unsigned short)f2bf(v.z);
            hv.w = (unsigned short)f2bf(v.w);
            *(ushort4*)&Hhi[(size_t)r * 128 + c4] = hv;
        }
        int g = batch[r];
        if (g != curg) {
            if (curg >= 0) {
                float* p = pbase + curg * 640;
                atomicAdd(p + 0, accp.x);
                atomicAdd(p + 1, accp.y);
                atomicAdd(p + 2, accp.z);
                atomicAdd(p + 3, accp.w);
            }
            curg = g;
            accp.x = accp.y = accp.z = accp.w = 0.f;
        }
        accp.x += v.x;
        accp.y += v.y;
        accp.z += v.z;
        accp.w += v.w;
    }
    if (curg >= 0) {
        float* p = pbase + curg * 640;
        atomicAdd(p + 0, accp.x);
        atomicAdd(p + 1, accp.y);
        atomicAdd(p + 2, accp.z);
        atomicAdd(p + 3, accp.w);
    }
}

extern "C" void kernel_launch(void* const* d_in, const int* in_sizes, int n_in,
                              void* d_out, int out_size, void* d_ws, size_t ws_size,
                              hipStream_t stream) {
    const int* batch = (const int*)d_in[0];
    const float* x = (const float*)d_in[1];
    const int* edge_index = (const int*)d_in[2];
    const float* edge_attr = (const float*)d_in[3];
    const float* edge_weight = (const float*)d_in[4];
    const float* W_atom = (const float*)d_in[5];
    const float* b_atom = (const float*)d_in[6];
    const float* W_bond = (const float*)d_in[7];
    const float* b_bond = (const float*)d_in[8];
    const float* Wl = (const float*)d_in[9];
    const float* bl = (const float*)d_in[10];
    const float* Wr = (const float*)d_in[11];
    const float* gamma = (const float*)d_in[12];
    const float* beta = (const float*)d_in[13];
    float* out = (float*)d_out;

    // ---- workspace layout ----
    char* ws = (char*)d_ws;
    size_t off = 0;
    auto alloc = [&](size_t bytes) -> void* {
        void* p = ws + off;
        off += (bytes + 255) & ~(size_t)255;
        return p;
    };
    short* Hhi = (short*)alloc((size_t)NNODES * 128 * 2);
    short* Ahi = (short*)alloc((size_t)NNODES * 128 * 2);
    short* Cbf = (short*)alloc((size_t)NNODES * 128 * 2);
    short* Ehi = (short*)alloc((size_t)NNODES * 128 * 2);
    int* epk = (int*)alloc((size_t)NEDGES * 32);
    int2* epg = (int2*)alloc((size_t)NEDGES * 8);
    int* rowptr = (int*)alloc((size_t)(NNODES + 1) * 4);
    int* cursor = (int*)alloc((size_t)NNODES * 4);
    int* deg = (int*)alloc((size_t)NNODES * 4);
    float* stat = (float*)alloc(NLAYERS * 256 * 4);
    int* local_excl = (int*)alloc((size_t)NNODES * 4);
    int* part = (int*)alloc(SCAN_BLOCKS * 4);
    int* blockoff = (int*)alloc(SCAN_BLOCKS * 4);
    short* Bf = (short*)alloc((size_t)NLAYERS * 65536 * 2);

    // ---- preprocessing ----
    init_kernel<<<(NGRAPHS * 640 + 255) / 256, 256, 0, stream>>>(out, deg, stat);
    deg_kernel<<<(NEDGES + 255) / 256, 256, 0, stream>>>(edge_index, deg);
    scan1<<<SCAN_BLOCKS, 256, 0, stream>>>(deg, local_excl, part);
    scan2<<<1, 256, 0, stream>>>(part, blockoff, rowptr);
    scan3<<<SCAN_BLOCKS, 256, 0, stream>>>(local_excl, blockoff, rowptr, cursor);
    edge_fill<<<(NEDGES + 255) / 256, 256, 0, stream>>>(edge_index, edge_weight,
                                                        edge_attr, cursor, epk);
    prep2<<<NSB + EAB + BPB, 256, 0, stream>>>(rowptr, epk, epg, W_bond, b_bond, Ehi,
                                               x, W_atom, b_atom, Hhi, Wl, Wr, Bf);

    // ---- layers ----
    for (int i = 0; i < NLAYERS; i++) {
        agg_kernel<<<(NNODES + 7) / 8, 256, 0, stream>>>(Hhi, Ehi, rowptr, epg, Ahi);
        layer_gemm<<<(NNODES + 63) / 64, 256, 0, stream>>>(Ahi, Hhi,
                                                           Bf + (size_t)i * 65536,
                                                           bl + i * 128, Cbf,
                                                           stat + i * 256);
        int last = (i == NLAYERS - 1);
        bn_apply<<<(NNODES + 255) / 256, 256, 0, stream>>>(
            Cbf, Hhi, last ? (out + (size_t)NGRAPHS * 640) : nullptr,
            stat + i * 256, gamma + i * 128, beta + i * 128, batch, out, i,
            last ? 0 : 1);
    }
}

// Round 13
// 644.105 us; speedup vs baseline: 1.2879x; 1.1417x over previous
//
#include <hip/hip_runtime.h>
#include <hip/hip_bf16.h>

#define NNODES 50000
#define NEDGES 600000
#define NGRAPHS 128
#define EMB 128
#define NLAYERS 5
#define BN_EPS 1e-5f
#define SCAN_BLOCKS ((NNODES + 255) / 256)    // 196
#define NSB ((NNODES + 255) / 256)            // 196 node_S_bond blocks
#define EAB ((NNODES + 31) / 32)              // 1563 enc_atom blocks
#define BPB ((NLAYERS * 32768 + 255) / 256)   // 640 bprep blocks

typedef short s16x8 __attribute__((ext_vector_type(8)));
typedef float f32x16 __attribute__((ext_vector_type(16)));

__device__ __forceinline__ short f2bf(float f) {
    unsigned u = __builtin_bit_cast(unsigned, f);
    unsigned r = (u + 0x7fffu + ((u >> 16) & 1u)) >> 16;  // RNE
    return (short)r;
}
__device__ __forceinline__ float bf2f(short s) {
    return __builtin_bit_cast(float, ((unsigned)(unsigned short)s) << 16);
}

// ---------------- init: zero pool region, deg, stat (replaces 3 memsets) -----
__global__ __launch_bounds__(256) void init_kernel(float* __restrict__ pool,
                                                   int* __restrict__ deg,
                                                   float* __restrict__ stat) {
    int i = blockIdx.x * 256 + threadIdx.x;
    if (i < NGRAPHS * 640) pool[i] = 0.f;
    if (i < NNODES) deg[i] = 0;
    if (i < NLAYERS * 256) stat[i] = 0.f;
}

// ---------------- deg histogram (int atomics only) ---------------------------
__global__ __launch_bounds__(256) void deg_kernel(const int* __restrict__ ei,
                                                  int* __restrict__ deg) {
    int e = blockIdx.x * 256 + threadIdx.x;
    if (e >= NEDGES) return;
    atomicAdd(&deg[ei[NEDGES + e]], 1);
}

// ---------------- multi-block scan (3 fast dispatches) -----------------------
__global__ __launch_bounds__(256) void scan1(const int* __restrict__ deg,
                                             int* __restrict__ local_excl,
                                             int* __restrict__ part) {
    __shared__ int sh[256];
    int t = threadIdx.x;
    int i = blockIdx.x * 256 + t;
    int v = (i < NNODES) ? deg[i] : 0;
    sh[t] = v;
    __syncthreads();
    for (int off = 1; off < 256; off <<= 1) {
        int u = (t >= off) ? sh[t - off] : 0;
        __syncthreads();
        sh[t] += u;
        __syncthreads();
    }
    if (i < NNODES) local_excl[i] = sh[t] - v;
    if (t == 255) part[blockIdx.x] = sh[255];
}

__global__ __launch_bounds__(256) void scan2(int* __restrict__ part,
                                             int* __restrict__ blockoff,
                                             int* __restrict__ rowptr) {
    __shared__ int sh[256];
    int t = threadIdx.x;
    int v = (t < SCAN_BLOCKS) ? part[t] : 0;
    sh[t] = v;
    __syncthreads();
    for (int off = 1; off < 256; off <<= 1) {
        int u = (t >= off) ? sh[t - off] : 0;
        __syncthreads();
        sh[t] += u;
        __syncthreads();
    }
    if (t < SCAN_BLOCKS) blockoff[t] = sh[t] - v;
    if (t == 255) rowptr[NNODES] = sh[255];
}

__global__ __launch_bounds__(256) void scan3(const int* __restrict__ local_excl,
                                             const int* __restrict__ blockoff,
                                             int* __restrict__ rowptr,
                                             int* __restrict__ cursor) {
    int i = blockIdx.x * 256 + threadIdx.x;
    if (i >= NNODES) return;
    int v = local_excl[i] + blockoff[blockIdx.x];
    rowptr[i] = v;
    cursor[i] = v;
}

// ---------------- fill CSR: 32B record {src, w, 11x bf16 attr, pad} ----------
__global__ __launch_bounds__(256) void edge_fill(const int* __restrict__ ei,
                                                 const float* __restrict__ ew,
                                                 const float* __restrict__ eattr,
                                                 int* __restrict__ cursor,
                                                 int* __restrict__ epk) {
    int e = blockIdx.x * 256 + threadIdx.x;
    if (e >= NEDGES) return;
    int src = ei[e];
    int dst = ei[NEDGES + e];
    int pos = atomicAdd(&cursor[dst], 1);
    int pk[8];
    pk[0] = src;
    pk[1] = __float_as_int(ew[e]);
    unsigned short a[12];
#pragma unroll
    for (int j = 0; j < 11; j++) a[j] = (unsigned short)f2bf(eattr[e * 11 + j]);
    a[11] = 0;
#pragma unroll
    for (int j = 0; j < 6; j++)
        pk[2 + j] = (int)a[2 * j] | ((int)a[2 * j + 1] << 16);
    int* dstp = epk + (size_t)pos * 8;
    *(int4*)dstp = *(int4*)pk;
    *(int4*)(dstp + 4) = *(int4*)(pk + 4);
}

// ---------------- prep2: heterogeneous {node_S+enc_bond | enc_atom | bprep} --
__global__ __launch_bounds__(256) void prep2(const int* __restrict__ rowptr,
                                             const int* __restrict__ epk,
                                             int2* __restrict__ epg,
                                             const float* __restrict__ Wb,
                                             const float* __restrict__ bbond,
                                             short* __restrict__ Ehi,
                                             const float* __restrict__ X,
                                             const float* __restrict__ Wa,
                                             const float* __restrict__ ba,
                                             short* __restrict__ Hhi,
                                             const float* __restrict__ Wl,
                                             const float* __restrict__ Wr,
                                             short* __restrict__ Bf) {
    __shared__ float shpool[1664];  // 6656 B, aliased by both branches
    int blk = blockIdx.x;
    int t = threadIdx.x;

    if (blk < NSB) {
        // ---- node_S + enc_bond fused: thread-per-node ----
        float* Wb_s = shpool;        // 11*128 = 1408
        float* bb_s = shpool + 1408; // 128
        for (int i = t; i < 1408; i += 256) Wb_s[i] = Wb[i];
        if (t < 128) bb_s[t] = bbond[t];
        __syncthreads();
        int node = blk * 256 + t;
        if (node >= NNODES) return;
        int b = rowptr[node], e = rowptr[node + 1];
        float s[11];
#pragma unroll
        for (int j = 0; j < 11; j++) s[j] = 0.f;
        float ws = 0.f;
        for (int p = b; p < e; p++) {
            const int* pk = epk + (size_t)p * 8;
            int4 lo = *(const int4*)pk;
            int4 hi = *(const int4*)(pk + 4);
            float w = __int_as_float(lo.y);
            ws += w;
            epg[p] = make_int2(lo.x, lo.y);   // compact {src,w} gather record
            int packed[6] = {lo.z, lo.w, hi.x, hi.y, hi.z, hi.w};
#pragma unroll
            for (int j = 0; j < 11; j++) {
                short v = (short)((packed[j >> 1] >> ((j & 1) * 16)) & 0xffff);
                s[j] += bf2f(v) * w;
            }
        }
        short* erow = Ehi + (size_t)node * 128;
#pragma unroll
        for (int c8 = 0; c8 < 16; c8++) {
            s16x8 o;
#pragma unroll
            for (int jj = 0; jj < 8; jj++) {
                int c = c8 * 8 + jj;
                float a = bb_s[c] * ws;
#pragma unroll
                for (int j = 0; j < 11; j++) a += s[j] * Wb_s[j * 128 + c];
                o[jj] = f2bf(a);
            }
            *(s16x8*)(erow + c8 * 8) = o;
        }
    } else if (blk < NSB + EAB) {
        // ---- enc_atom: h0 = x @ W_atom + b_atom -> bf16 ----
        float* as = shpool;  // 32*48 = 1536
        int row0 = (blk - NSB) * 32;
        for (int i = t; i < 32 * 48; i += 256) {
            int r = i / 48, c = i - r * 48;
            int gr = row0 + r;
            as[i] = (gr < NNODES) ? X[gr * 48 + c] : 0.f;
        }
        __syncthreads();
        int c = t & 127, rh = t >> 7;
        float acc[16];
#pragma unroll
        for (int i = 0; i < 16; i++) acc[i] = 0.f;
        for (int k = 0; k < 48; k++) {
            float w = Wa[k * 128 + c];
#pragma unroll
            for (int i = 0; i < 16; i++) acc[i] += as[(rh * 16 + i) * 48 + k] * w;
        }
        float bb = ba[c];
        for (int i = 0; i < 16; i++) {
            int gr = row0 + rh * 16 + i;
            if (gr < NNODES) Hhi[(size_t)gr * 128 + c] = f2bf(acc[i] + bb);
        }
    } else {
        // ---- bprep: weight fragments, hi/lo planes ----
        int idx = (blk - NSB - EAB) * 256 + t;
        if (idx >= NLAYERS * 32768) return;
        int layer = idx >> 15;
        int r = idx & 32767;
        int k = r >> 7, col = r & 127;
        float w = (k < 128) ? Wl[layer * 16384 + k * 128 + col]
                            : Wr[layer * 16384 + (k - 128) * 128 + col];
        short hi = f2bf(w);
        short lo = f2bf(w - bf2f(hi));
        int ks = k >> 4, half = (k >> 3) & 1, j = k & 7;
        int nt = col >> 5, n32 = col & 31;
        int fo = ((nt * 2 + half) * 32 + n32) * 8 + j;
        short* base = Bf + (size_t)layer * 65536 + ks * 4096;
        base[fo] = hi;
        base[2048 + fo] = lo;
    }
}

// ---------------- per-layer aggregation: bf16 gather -> Ahi plane ------------
__global__ __launch_bounds__(256) void agg_kernel(const short* __restrict__ Hhi,
                                                  const short* __restrict__ Ehi,
                                                  const int* __restrict__ rowptr,
                                                  const int2* __restrict__ epg,
                                                  short* __restrict__ Ahi) {
    int t = threadIdx.x;
    int lane = t & 31, grp = t >> 5;
    int c4 = lane * 4;
    int node = blockIdx.x * 8 + grp;
    if (node >= NNODES) return;
    int b = rowptr[node], e = rowptr[node + 1];
    float s0 = 0.f, s1 = 0.f, s2 = 0.f, s3 = 0.f;
    int p = b;
    for (; p + 1 < e; p += 2) {
        int2 pk0 = epg[p], pk1 = epg[p + 1];
        float w0 = __int_as_float(pk0.y), w1 = __int_as_float(pk1.y);
        ushort4 h0 = *(const ushort4*)&Hhi[(size_t)pk0.x * 128 + c4];
        ushort4 h1 = *(const ushort4*)&Hhi[(size_t)pk1.x * 128 + c4];
        s0 += bf2f((short)h0.x) * w0 + bf2f((short)h1.x) * w1;
        s1 += bf2f((short)h0.y) * w0 + bf2f((short)h1.y) * w1;
        s2 += bf2f((short)h0.z) * w0 + bf2f((short)h1.z) * w1;
        s3 += bf2f((short)h0.w) * w0 + bf2f((short)h1.w) * w1;
    }
    if (p < e) {
        int2 pk0 = epg[p];
        float w0 = __int_as_float(pk0.y);
        ushort4 h0 = *(const ushort4*)&Hhi[(size_t)pk0.x * 128 + c4];
        s0 += bf2f((short)h0.x) * w0;
        s1 += bf2f((short)h0.y) * w0;
        s2 += bf2f((short)h0.z) * w0;
        s3 += bf2f((short)h0.w) * w0;
    }
    float inv = 1.f / fmaxf((float)(e - b), 1.f);
    ushort4 ea = *(const ushort4*)&Ehi[(size_t)node * 128 + c4];
    ushort4 o;
    o.x = (unsigned short)f2bf((s0 + bf2f((short)ea.x)) * inv);
    o.y = (unsigned short)f2bf((s1 + bf2f((short)ea.y)) * inv);
    o.z = (unsigned short)f2bf((s2 + bf2f((short)ea.z)) * inv);
    o.w = (unsigned short)f2bf((s3 + bf2f((short)ea.w)) * inv);
    *(ushort4*)&Ahi[(size_t)node * 128 + c4] = o;
}

// ---------------- MFMA GEMM (32x32x16, A hi-only, r10 geometry) --------------
// Wave tile 32 rows x 128 cols, full K=256. Block = 4 waves = 128 rows.
// Register double-buffer: kstep k+1's A+B fragments prefetched before k's MFMAs.
__global__ __launch_bounds__(256) void layer_gemm(const short* __restrict__ Ahi,
                                                  const short* __restrict__ Hhi,
                                                  const short* __restrict__ Bf,
                                                  const float* __restrict__ bias,
                                                  short* __restrict__ Cbf,
                                                  float* __restrict__ stat) {
    __shared__ float s_s[128], s_q[128];
    int t = threadIdx.x;
    int wave = t >> 6, lane = t & 63;
    int n32 = lane & 31, half = lane >> 5;
    int row0 = blockIdx.x * 128 + wave * 32;

    if (t < 128) { s_s[t] = 0.f; s_q[t] = 0.f; }
    __syncthreads();

    int myrow = row0 + n32;
    bool rowok = myrow < NNODES;
    size_t rbase = (size_t)myrow * 128;
    int acol = half * 8;

    f32x16 acc[4];
#pragma unroll
    for (int i = 0; i < 4; i++) acc[i] = (f32x16)(0.f);

    const short* bb0 = Bf + half * 256 + n32 * 8;

    s16x8 ah = {0, 0, 0, 0, 0, 0, 0, 0};
    s16x8 bh[4], bl[4];
    if (rowok) ah = *(const s16x8*)(Ahi + rbase + acol);
#pragma unroll
    for (int nt = 0; nt < 4; nt++) {
        bh[nt] = *(const s16x8*)(bb0 + nt * 512);
        bl[nt] = *(const s16x8*)(bb0 + 2048 + nt * 512);
    }

#pragma unroll
    for (int ks = 0; ks < 16; ks++) {
        s16x8 ah2 = {0, 0, 0, 0, 0, 0, 0, 0};
        s16x8 bh2[4], bl2[4];
        if (ks < 15) {
            int kn = ks + 1;
            if (rowok) {
                const short* hs = (kn < 8 ? Ahi : Hhi) + rbase + (kn & 7) * 16 + acol;
                ah2 = *(const s16x8*)hs;
            }
            const short* bbn = bb0 + kn * 4096;
#pragma unroll
            for (int nt = 0; nt < 4; nt++) {
                bh2[nt] = *(const s16x8*)(bbn + nt * 512);
                bl2[nt] = *(const s16x8*)(bbn + 2048 + nt * 512);
            }
        }
#pragma unroll
        for (int nt = 0; nt < 4; nt++) {
            acc[nt] = __builtin_amdgcn_mfma_f32_32x32x16_bf16(ah, bh[nt], acc[nt], 0, 0, 0);
            acc[nt] = __builtin_amdgcn_mfma_f32_32x32x16_bf16(ah, bl[nt], acc[nt], 0, 0, 0);
        }
        if (ks < 15) {
            ah = ah2;
#pragma unroll
            for (int nt = 0; nt < 4; nt++) {
                bh[nt] = bh2[nt];
                bl[nt] = bl2[nt];
            }
        }
    }

    // epilogue: bias, bf16 C write, fused BN partial stats
#pragma unroll
    for (int nt = 0; nt < 4; nt++) {
        int col = nt * 32 + n32;
        float bb = bias[col];
        float ss = 0.f, qq = 0.f;
#pragma unroll
        for (int reg = 0; reg < 16; reg++) {
            int r = row0 + (reg & 3) + 8 * (reg >> 2) + 4 * half;
            if (r < NNODES) {
                float v = acc[nt][reg] + bb;
                Cbf[(size_t)r * 128 + col] = f2bf(v);
                ss += v;
                qq += v * v;
            }
        }
        ss += __shfl_xor(ss, 32);
        qq += __shfl_xor(qq, 32);
        if (half == 0) {
            atomicAdd(&s_s[col], ss);
            atomicAdd(&s_q[col], qq);
        }
    }
    __syncthreads();
    if (t < 128) {
        atomicAdd(&stat[t], s_s[t]);
        atomicAdd(&stat[128 + t], s_q[t]);
    }
}

// ---------------- BN apply (+inline coef) + ReLU + xpool ---------------------
__global__ __launch_bounds__(256) void bn_apply(const short* __restrict__ Cbf,
                                                short* __restrict__ Hhi,
                                                float* __restrict__ Hf32,
                                                const float* __restrict__ stat,
                                                const float* __restrict__ gamma,
                                                const float* __restrict__ beta,
                                                const int* __restrict__ batch,
                                                float* __restrict__ pool,
                                                int layer, int relu) {
    __shared__ float csc[128], csh[128];
    int t = threadIdx.x;
    if (t < 128) {
        const float invM = 1.f / (float)NNODES;
        float mu = stat[t] * invM;
        float var = stat[128 + t] * invM - mu * mu;
        float inv = rsqrtf(var + BN_EPS);
        float sc = gamma[t] * inv;
        csc[t] = sc;
        csh[t] = beta[t] - mu * sc;
    }
    __syncthreads();
    int lane = t & 31, grp = t >> 5;
    int c4 = lane * 4;
    float4 sc = *(const float4*)&csc[c4];
    float4 sh = *(const float4*)&csh[c4];
    int row0 = blockIdx.x * 256;
    float4 accp = {0.f, 0.f, 0.f, 0.f};
    int curg = -1;
    float* pbase = pool + layer * 128 + c4;
    for (int rr = grp; rr < 256; rr += 8) {
        int r = row0 + rr;
        if (r >= NNODES) break;
        ushort4 cv = *(const ushort4*)&Cbf[(size_t)r * 128 + c4];
        float4 v;
        v.x = bf2f((short)cv.x) * sc.x + sh.x;
        v.y = bf2f((short)cv.y) * sc.y + sh.y;
        v.z = bf2f((short)cv.z) * sc.z + sh.z;
        v.w = bf2f((short)cv.w) * sc.w + sh.w;
        if (relu) {
            v.x = fmaxf(v.x, 0.f);
            v.y = fmaxf(v.y, 0.f);
            v.z = fmaxf(v.z, 0.f);
            v.w = fmaxf(v.w, 0.f);
        }
        if (Hf32) {
            *(float4*)&Hf32[(size_t)r * 128 + c4] = v;
        } else {
            ushort4 hv;
            hv.x = (unsigned short)f2bf(v.x);
            hv.y = (unsigned short)f2bf(v.y);
            hv.z = (unsigned short)f2bf(v.z);
            hv.w = (unsigned short)f2bf(v.w);
            *(ushort4*)&Hhi[(size_t)r * 128 + c4] = hv;
        }
        int g = batch[r];
        if (g != curg) {
            if (curg >= 0) {
                float* p = pbase + curg * 640;
                atomicAdd(p + 0, accp.x);
                atomicAdd(p + 1, accp.y);
                atomicAdd(p + 2, accp.z);
                atomicAdd(p + 3, accp.w);
            }
            curg = g;
            accp.x = accp.y = accp.z = accp.w = 0.f;
        }
        accp.x += v.x;
        accp.y += v.y;
        accp.z += v.z;
        accp.w += v.w;
    }
    if (curg >= 0) {
        float* p = pbase + curg * 640;
        atomicAdd(p + 0, accp.x);
        atomicAdd(p + 1, accp.y);
        atomicAdd(p + 2, accp.z);
        atomicAdd(p + 3, accp.w);
    }
}

extern "C" void kernel_launch(void* const* d_in, const int* in_sizes, int n_in,
                              void* d_out, int out_size, void* d_ws, size_t ws_size,
                              hipStream_t stream) {
    const int* batch = (const int*)d_in[0];
    const float* x = (const float*)d_in[1];
    const int* edge_index = (const int*)d_in[2];
    const float* edge_attr = (const float*)d_in[3];
    const float* edge_weight = (const float*)d_in[4];
    const float* W_atom = (const float*)d_in[5];
    const float* b_atom = (const float*)d_in[6];
    const float* W_bond = (const float*)d_in[7];
    const float* b_bond = (const float*)d_in[8];
    const float* Wl = (const float*)d_in[9];
    const float* bl = (const float*)d_in[10];
    const float* Wr = (const float*)d_in[11];
    const float* gamma = (const float*)d_in[12];
    const float* beta = (const float*)d_in[13];
    float* out = (float*)d_out;

    // ---- workspace layout ----
    char* ws = (char*)d_ws;
    size_t off = 0;
    auto alloc = [&](size_t bytes) -> void* {
        void* p = ws + off;
        off += (bytes + 255) & ~(size_t)255;
        return p;
    };
    short* Hhi = (short*)alloc((size_t)NNODES * 128 * 2);
    short* Ahi = (short*)alloc((size_t)NNODES * 128 * 2);
    short* Cbf = (short*)alloc((size_t)NNODES * 128 * 2);
    short* Ehi = (short*)alloc((size_t)NNODES * 128 * 2);
    int* epk = (int*)alloc((size_t)NEDGES * 32);
    int2* epg = (int2*)alloc((size_t)NEDGES * 8);
    int* rowptr = (int*)alloc((size_t)(NNODES + 1) * 4);
    int* cursor = (int*)alloc((size_t)NNODES * 4);
    int* deg = (int*)alloc((size_t)NNODES * 4);
    float* stat = (float*)alloc(NLAYERS * 256 * 4);
    int* local_excl = (int*)alloc((size_t)NNODES * 4);
    int* part = (int*)alloc(SCAN_BLOCKS * 4);
    int* blockoff = (int*)alloc(SCAN_BLOCKS * 4);
    short* Bf = (short*)alloc((size_t)NLAYERS * 65536 * 2);

    // ---- preprocessing ----
    init_kernel<<<(NGRAPHS * 640 + 255) / 256, 256, 0, stream>>>(out, deg, stat);
    deg_kernel<<<(NEDGES + 255) / 256, 256, 0, stream>>>(edge_index, deg);
    scan1<<<SCAN_BLOCKS, 256, 0, stream>>>(deg, local_excl, part);
    scan2<<<1, 256, 0, stream>>>(part, blockoff, rowptr);
    scan3<<<SCAN_BLOCKS, 256, 0, stream>>>(local_excl, blockoff, rowptr, cursor);
    edge_fill<<<(NEDGES + 255) / 256, 256, 0, stream>>>(edge_index, edge_weight,
                                                        edge_attr, cursor, epk);
    prep2<<<NSB + EAB + BPB, 256, 0, stream>>>(rowptr, epk, epg, W_bond, b_bond, Ehi,
                                               x, W_atom, b_atom, Hhi, Wl, Wr, Bf);

    // ---- layers ----
    for (int i = 0; i < NLAYERS; i++) {
        agg_kernel<<<(NNODES + 7) / 8, 256, 0, stream>>>(Hhi, Ehi, rowptr, epg, Ahi);
        layer_gemm<<<(NNODES + 127) / 128, 256, 0, stream>>>(Ahi, Hhi,
                                                             Bf + (size_t)i * 65536,
                                                             bl + i * 128, Cbf,
                                                             stat + i * 256);
        int last = (i == NLAYERS - 1);
        bn_apply<<<(NNODES + 255) / 256, 256, 0, stream>>>(
            Cbf, Hhi, last ? (out + (size_t)NGRAPHS * 640) : nullptr,
            stat + i * 256, gamma + i * 128, beta + i * 128, batch, out, i,
            last ? 0 : 1);
    }
}

// Round 14
// 622.065 us; speedup vs baseline: 1.3335x; 1.0354x over previous
//
#include <hip/hip_runtime.h>
#include <hip/hip_bf16.h>

#define NNODES 50000
#define NEDGES 600000
#define NGRAPHS 128
#define EMB 128
#define NLAYERS 5
#define BN_EPS 1e-5f
#define SCAN_BLOCKS ((NNODES + 255) / 256)    // 196
#define NSB ((NNODES + 255) / 256)            // 196 node_S_bond blocks
#define EAB ((NNODES + 31) / 32)              // 1563 enc_atom blocks
#define BPB ((NLAYERS * 32768 + 255) / 256)   // 640 bprep blocks

typedef short s16x8 __attribute__((ext_vector_type(8)));
typedef float f32x16 __attribute__((ext_vector_type(16)));

__device__ __forceinline__ short f2bf(float f) {
    unsigned u = __builtin_bit_cast(unsigned, f);
    unsigned r = (u + 0x7fffu + ((u >> 16) & 1u)) >> 16;  // RNE
    return (short)r;
}
__device__ __forceinline__ float bf2f(short s) {
    return __builtin_bit_cast(float, ((unsigned)(unsigned short)s) << 16);
}

// ---------------- init: zero pool region, deg, stat (replaces 3 memsets) -----
__global__ __launch_bounds__(256) void init_kernel(float* __restrict__ pool,
                                                   int* __restrict__ deg,
                                                   float* __restrict__ stat) {
    int i = blockIdx.x * 256 + threadIdx.x;
    if (i < NGRAPHS * 640) pool[i] = 0.f;
    if (i < NNODES) deg[i] = 0;
    if (i < NLAYERS * 256) stat[i] = 0.f;
}

// ---------------- deg histogram (int atomics only) ---------------------------
__global__ __launch_bounds__(256) void deg_kernel(const int* __restrict__ ei,
                                                  int* __restrict__ deg) {
    int e = blockIdx.x * 256 + threadIdx.x;
    if (e >= NEDGES) return;
    atomicAdd(&deg[ei[NEDGES + e]], 1);
}

// ---------------- multi-block scan (3 fast dispatches) -----------------------
__global__ __launch_bounds__(256) void scan1(const int* __restrict__ deg,
                                             int* __restrict__ local_excl,
                                             int* __restrict__ part) {
    __shared__ int sh[256];
    int t = threadIdx.x;
    int i = blockIdx.x * 256 + t;
    int v = (i < NNODES) ? deg[i] : 0;
    sh[t] = v;
    __syncthreads();
    for (int off = 1; off < 256; off <<= 1) {
        int u = (t >= off) ? sh[t - off] : 0;
        __syncthreads();
        sh[t] += u;
        __syncthreads();
    }
    if (i < NNODES) local_excl[i] = sh[t] - v;
    if (t == 255) part[blockIdx.x] = sh[255];
}

__global__ __launch_bounds__(256) void scan2(int* __restrict__ part,
                                             int* __restrict__ blockoff,
                                             int* __restrict__ rowptr) {
    __shared__ int sh[256];
    int t = threadIdx.x;
    int v = (t < SCAN_BLOCKS) ? part[t] : 0;
    sh[t] = v;
    __syncthreads();
    for (int off = 1; off < 256; off <<= 1) {
        int u = (t >= off) ? sh[t - off] : 0;
        __syncthreads();
        sh[t] += u;
        __syncthreads();
    }
    if (t < SCAN_BLOCKS) blockoff[t] = sh[t] - v;
    if (t == 255) rowptr[NNODES] = sh[255];
}

__global__ __launch_bounds__(256) void scan3(const int* __restrict__ local_excl,
                                             const int* __restrict__ blockoff,
                                             int* __restrict__ rowptr,
                                             int* __restrict__ cursor) {
    int i = blockIdx.x * 256 + threadIdx.x;
    if (i >= NNODES) return;
    int v = local_excl[i] + blockoff[blockIdx.x];
    rowptr[i] = v;
    cursor[i] = v;
}

// ---------------- fill CSR: 32B record {src, w, 11x bf16 attr, pad} ----------
__global__ __launch_bounds__(256) void edge_fill(const int* __restrict__ ei,
                                                 const float* __restrict__ ew,
                                                 const float* __restrict__ eattr,
                                                 int* __restrict__ cursor,
                                                 int* __restrict__ epk) {
    int e = blockIdx.x * 256 + threadIdx.x;
    if (e >= NEDGES) return;
    int src = ei[e];
    int dst = ei[NEDGES + e];
    int pos = atomicAdd(&cursor[dst], 1);
    int pk[8];
    pk[0] = src;
    pk[1] = __float_as_int(ew[e]);
    unsigned short a[12];
#pragma unroll
    for (int j = 0; j < 11; j++) a[j] = (unsigned short)f2bf(eattr[e * 11 + j]);
    a[11] = 0;
#pragma unroll
    for (int j = 0; j < 6; j++)
        pk[2 + j] = (int)a[2 * j] | ((int)a[2 * j + 1] << 16);
    int* dstp = epk + (size_t)pos * 8;
    *(int4*)dstp = *(int4*)pk;
    *(int4*)(dstp + 4) = *(int4*)(pk + 4);
}

// ---------------- prep2: heterogeneous {node_S+enc_bond | enc_atom | bprep} --
__global__ __launch_bounds__(256) void prep2(const int* __restrict__ rowptr,
                                             const int* __restrict__ epk,
                                             int2* __restrict__ epg,
                                             const float* __restrict__ Wb,
                                             const float* __restrict__ bbond,
                                             short* __restrict__ Ehi,
                                             const float* __restrict__ X,
                                             const float* __restrict__ Wa,
                                             const float* __restrict__ ba,
                                             short* __restrict__ Hhi,
                                             const float* __restrict__ Wl,
                                             const float* __restrict__ Wr,
                                             short* __restrict__ Bf) {
    __shared__ float shpool[1664];  // 6656 B, aliased by both branches
    int blk = blockIdx.x;
    int t = threadIdx.x;

    if (blk < NSB) {
        // ---- node_S + enc_bond fused: thread-per-node ----
        float* Wb_s = shpool;        // 11*128 = 1408
        float* bb_s = shpool + 1408; // 128
        for (int i = t; i < 1408; i += 256) Wb_s[i] = Wb[i];
        if (t < 128) bb_s[t] = bbond[t];
        __syncthreads();
        int node = blk * 256 + t;
        if (node >= NNODES) return;
        int b = rowptr[node], e = rowptr[node + 1];
        float s[11];
#pragma unroll
        for (int j = 0; j < 11; j++) s[j] = 0.f;
        float ws = 0.f;
        for (int p = b; p < e; p++) {
            const int* pk = epk + (size_t)p * 8;
            int4 lo = *(const int4*)pk;
            int4 hi = *(const int4*)(pk + 4);
            float w = __int_as_float(lo.y);
            ws += w;
            epg[p] = make_int2(lo.x, lo.y);   // compact {src,w} gather record
            int packed[6] = {lo.z, lo.w, hi.x, hi.y, hi.z, hi.w};
#pragma unroll
            for (int j = 0; j < 11; j++) {
                short v = (short)((packed[j >> 1] >> ((j & 1) * 16)) & 0xffff);
                s[j] += bf2f(v) * w;
            }
        }
        short* erow = Ehi + (size_t)node * 128;
#pragma unroll
        for (int c8 = 0; c8 < 16; c8++) {
            s16x8 o;
#pragma unroll
            for (int jj = 0; jj < 8; jj++) {
                int c = c8 * 8 + jj;
                float a = bb_s[c] * ws;
#pragma unroll
                for (int j = 0; j < 11; j++) a += s[j] * Wb_s[j * 128 + c];
                o[jj] = f2bf(a);
            }
            *(s16x8*)(erow + c8 * 8) = o;
        }
    } else if (blk < NSB + EAB) {
        // ---- enc_atom: h0 = x @ W_atom + b_atom -> bf16 ----
        float* as = shpool;  // 32*48 = 1536
        int row0 = (blk - NSB) * 32;
        for (int i = t; i < 32 * 48; i += 256) {
            int r = i / 48, c = i - r * 48;
            int gr = row0 + r;
            as[i] = (gr < NNODES) ? X[gr * 48 + c] : 0.f;
        }
        __syncthreads();
        int c = t & 127, rh = t >> 7;
        float acc[16];
#pragma unroll
        for (int i = 0; i < 16; i++) acc[i] = 0.f;
        for (int k = 0; k < 48; k++) {
            float w = Wa[k * 128 + c];
#pragma unroll
            for (int i = 0; i < 16; i++) acc[i] += as[(rh * 16 + i) * 48 + k] * w;
        }
        float bb = ba[c];
        for (int i = 0; i < 16; i++) {
            int gr = row0 + rh * 16 + i;
            if (gr < NNODES) Hhi[(size_t)gr * 128 + c] = f2bf(acc[i] + bb);
        }
    } else {
        // ---- bprep: weight fragments, hi/lo planes ----
        int idx = (blk - NSB - EAB) * 256 + t;
        if (idx >= NLAYERS * 32768) return;
        int layer = idx >> 15;
        int r = idx & 32767;
        int k = r >> 7, col = r & 127;
        float w = (k < 128) ? Wl[layer * 16384 + k * 128 + col]
                            : Wr[layer * 16384 + (k - 128) * 128 + col];
        short hi = f2bf(w);
        short lo = f2bf(w - bf2f(hi));
        int ks = k >> 4, half = (k >> 3) & 1, j = k & 7;
        int nt = col >> 5, n32 = col & 31;
        int fo = ((nt * 2 + half) * 32 + n32) * 8 + j;
        short* base = Bf + (size_t)layer * 65536 + ks * 4096;
        base[fo] = hi;
        base[2048 + fo] = lo;
    }
}

// ---------------- per-layer aggregation: 4-way unrolled bf16 gather ----------
__global__ __launch_bounds__(256) void agg_kernel(const short* __restrict__ Hhi,
                                                  const short* __restrict__ Ehi,
                                                  const int* __restrict__ rowptr,
                                                  const int2* __restrict__ epg,
                                                  short* __restrict__ Ahi) {
    int t = threadIdx.x;
    int lane = t & 31, grp = t >> 5;
    int c4 = lane * 4;
    int node = blockIdx.x * 8 + grp;
    if (node >= NNODES) return;
    int b = rowptr[node], e = rowptr[node + 1];
    float s0 = 0.f, s1 = 0.f, s2 = 0.f, s3 = 0.f;
    int p = b;
    for (; p + 3 < e; p += 4) {
        int2 e0 = epg[p], e1 = epg[p + 1], e2 = epg[p + 2], e3 = epg[p + 3];
        float w0 = __int_as_float(e0.y), w1 = __int_as_float(e1.y);
        float w2 = __int_as_float(e2.y), w3 = __int_as_float(e3.y);
        ushort4 h0 = *(const ushort4*)&Hhi[(size_t)e0.x * 128 + c4];
        ushort4 h1 = *(const ushort4*)&Hhi[(size_t)e1.x * 128 + c4];
        ushort4 h2 = *(const ushort4*)&Hhi[(size_t)e2.x * 128 + c4];
        ushort4 h3 = *(const ushort4*)&Hhi[(size_t)e3.x * 128 + c4];
        s0 += bf2f((short)h0.x) * w0 + bf2f((short)h1.x) * w1 +
              bf2f((short)h2.x) * w2 + bf2f((short)h3.x) * w3;
        s1 += bf2f((short)h0.y) * w0 + bf2f((short)h1.y) * w1 +
              bf2f((short)h2.y) * w2 + bf2f((short)h3.y) * w3;
        s2 += bf2f((short)h0.z) * w0 + bf2f((short)h1.z) * w1 +
              bf2f((short)h2.z) * w2 + bf2f((short)h3.z) * w3;
        s3 += bf2f((short)h0.w) * w0 + bf2f((short)h1.w) * w1 +
              bf2f((short)h2.w) * w2 + bf2f((short)h3.w) * w3;
    }
    for (; p < e; p++) {
        int2 pk0 = epg[p];
        float w0 = __int_as_float(pk0.y);
        ushort4 h0 = *(const ushort4*)&Hhi[(size_t)pk0.x * 128 + c4];
        s0 += bf2f((short)h0.x) * w0;
        s1 += bf2f((short)h0.y) * w0;
        s2 += bf2f((short)h0.z) * w0;
        s3 += bf2f((short)h0.w) * w0;
    }
    float inv = 1.f / fmaxf((float)(e - b), 1.f);
    ushort4 ea = *(const ushort4*)&Ehi[(size_t)node * 128 + c4];
    ushort4 o;
    o.x = (unsigned short)f2bf((s0 + bf2f((short)ea.x)) * inv);
    o.y = (unsigned short)f2bf((s1 + bf2f((short)ea.y)) * inv);
    o.z = (unsigned short)f2bf((s2 + bf2f((short)ea.z)) * inv);
    o.w = (unsigned short)f2bf((s3 + bf2f((short)ea.w)) * inv);
    *(ushort4*)&Ahi[(size_t)node * 128 + c4] = o;
}

// ---------------- MFMA GEMM (32x32x16, A hi-only, prefetch depth 2) ----------
// Wave tile 32 rows x 128 cols, full K=256. Block = 4 waves = 128 rows.
// Triple-buffer rotation: kstep k+2's fragments issued before k's MFMAs.
__global__ __launch_bounds__(256) void layer_gemm(const short* __restrict__ Ahi,
                                                  const short* __restrict__ Hhi,
                                                  const short* __restrict__ Bf,
                                                  const float* __restrict__ bias,
                                                  short* __restrict__ Cbf,
                                                  float* __restrict__ stat) {
    __shared__ float s_s[128], s_q[128];
    int t = threadIdx.x;
    int wave = t >> 6, lane = t & 63;
    int n32 = lane & 31, half = lane >> 5;
    int row0 = blockIdx.x * 128 + wave * 32;

    if (t < 128) { s_s[t] = 0.f; s_q[t] = 0.f; }
    __syncthreads();

    int myrow = row0 + n32;
    bool rowok = myrow < NNODES;
    size_t rbase = (size_t)myrow * 128;
    int acol = half * 8;

    f32x16 acc[4];
#pragma unroll
    for (int i = 0; i < 4; i++) acc[i] = (f32x16)(0.f);

    const short* bb0 = Bf + half * 256 + n32 * 8;

    s16x8 ahA = {0, 0, 0, 0, 0, 0, 0, 0}, ahB = {0, 0, 0, 0, 0, 0, 0, 0};
    s16x8 bhA[4], blA[4], bhB[4], blB[4];
    // prologue: ks 0 -> A, ks 1 -> B
    if (rowok) {
        ahA = *(const s16x8*)(Ahi + rbase + acol);
        ahB = *(const s16x8*)(Ahi + rbase + 16 + acol);
    }
#pragma unroll
    for (int nt = 0; nt < 4; nt++) {
        bhA[nt] = *(const s16x8*)(bb0 + nt * 512);
        blA[nt] = *(const s16x8*)(bb0 + 2048 + nt * 512);
        bhB[nt] = *(const s16x8*)(bb0 + 4096 + nt * 512);
        blB[nt] = *(const s16x8*)(bb0 + 4096 + 2048 + nt * 512);
    }

#pragma unroll
    for (int ks = 0; ks < 16; ks++) {
        s16x8 ahC = {0, 0, 0, 0, 0, 0, 0, 0};
        s16x8 bhC[4], blC[4];
        if (ks < 14) {
            int kn = ks + 2;
            if (rowok) {
                const short* hs = (kn < 8 ? Ahi : Hhi) + rbase + (kn & 7) * 16 + acol;
                ahC = *(const s16x8*)hs;
            }
            const short* bbn = bb0 + kn * 4096;
#pragma unroll
            for (int nt = 0; nt < 4; nt++) {
                bhC[nt] = *(const s16x8*)(bbn + nt * 512);
                blC[nt] = *(const s16x8*)(bbn + 2048 + nt * 512);
            }
        }
#pragma unroll
        for (int nt = 0; nt < 4; nt++) {
            acc[nt] = __builtin_amdgcn_mfma_f32_32x32x16_bf16(ahA, bhA[nt], acc[nt], 0, 0, 0);
            acc[nt] = __builtin_amdgcn_mfma_f32_32x32x16_bf16(ahA, blA[nt], acc[nt], 0, 0, 0);
        }
        // rotate A <= B <= C (fully unrolled loop: compiler renames, no movs)
        ahA = ahB;
        ahB = ahC;
#pragma unroll
        for (int nt = 0; nt < 4; nt++) {
            bhA[nt] = bhB[nt];
            blA[nt] = blB[nt];
            bhB[nt] = bhC[nt];
            blB[nt] = blC[nt];
        }
    }

    // epilogue: bias, bf16 C write, fused BN partial stats
#pragma unroll
    for (int nt = 0; nt < 4; nt++) {
        int col = nt * 32 + n32;
        float bb = bias[col];
        float ss = 0.f, qq = 0.f;
#pragma unroll
        for (int reg = 0; reg < 16; reg++) {
            int r = row0 + (reg & 3) + 8 * (reg >> 2) + 4 * half;
            if (r < NNODES) {
                float v = acc[nt][reg] + bb;
                Cbf[(size_t)r * 128 + col] = f2bf(v);
                ss += v;
                qq += v * v;
            }
        }
        ss += __shfl_xor(ss, 32);
        qq += __shfl_xor(qq, 32);
        if (half == 0) {
            atomicAdd(&s_s[col], ss);
            atomicAdd(&s_q[col], qq);
        }
    }
    __syncthreads();
    if (t < 128) {
        atomicAdd(&stat[t], s_s[t]);
        atomicAdd(&stat[128 + t], s_q[t]);
    }
}

// ---------------- BN apply (+inline coef) + ReLU + xpool ---------------------
__global__ __launch_bounds__(256) void bn_apply(const short* __restrict__ Cbf,
                                                short* __restrict__ Hhi,
                                                float* __restrict__ Hf32,
                                                const float* __restrict__ stat,
                                                const float* __restrict__ gamma,
                                                const float* __restrict__ beta,
                                                const int* __restrict__ batch,
                                                float* __restrict__ pool,
                                                int layer, int relu) {
    __shared__ float csc[128], csh[128];
    int t = threadIdx.x;
    if (t < 128) {
        const float invM = 1.f / (float)NNODES;
        float mu = stat[t] * invM;
        float var = stat[128 + t] * invM - mu * mu;
        float inv = rsqrtf(var + BN_EPS);
        float sc = gamma[t] * inv;
        csc[t] = sc;
        csh[t] = beta[t] - mu * sc;
    }
    __syncthreads();
    int lane = t & 31, grp = t >> 5;
    int c4 = lane * 4;
    float4 sc = *(const float4*)&csc[c4];
    float4 sh = *(const float4*)&csh[c4];
    int row0 = blockIdx.x * 256;
    float4 accp = {0.f, 0.f, 0.f, 0.f};
    int curg = -1;
    float* pbase = pool + layer * 128 + c4;
    for (int rr = grp; rr < 256; rr += 8) {
        int r = row0 + rr;
        if (r >= NNODES) break;
        ushort4 cv = *(const ushort4*)&Cbf[(size_t)r * 128 + c4];
        float4 v;
        v.x = bf2f((short)cv.x) * sc.x + sh.x;
        v.y = bf2f((short)cv.y) * sc.y + sh.y;
        v.z = bf2f((short)cv.z) * sc.z + sh.z;
        v.w = bf2f((short)cv.w) * sc.w + sh.w;
        if (relu) {
            v.x = fmaxf(v.x, 0.f);
            v.y = fmaxf(v.y, 0.f);
            v.z = fmaxf(v.z, 0.f);
            v.w = fmaxf(v.w, 0.f);
        }
        if (Hf32) {
            *(float4*)&Hf32[(size_t)r * 128 + c4] = v;
        } else {
            ushort4 hv;
            hv.x = (unsigned short)f2bf(v.x);
            hv.y = (unsigned short)f2bf(v.y);
            hv.z = (unsigned short)f2bf(v.z);
            hv.w = (unsigned short)f2bf(v.w);
            *(ushort4*)&Hhi[(size_t)r * 128 + c4] = hv;
        }
        int g = batch[r];
        if (g != curg) {
            if (curg >= 0) {
                float* p = pbase + curg * 640;
                atomicAdd(p + 0, accp.x);
                atomicAdd(p + 1, accp.y);
                atomicAdd(p + 2, accp.z);
                atomicAdd(p + 3, accp.w);
            }
            curg = g;
            accp.x = accp.y = accp.z = accp.w = 0.f;
        }
        accp.x += v.x;
        accp.y += v.y;
        accp.z += v.z;
        accp.w += v.w;
    }
    if (curg >= 0) {
        float* p = pbase + curg * 640;
        atomicAdd(p + 0, accp.x);
        atomicAdd(p + 1, accp.y);
        atomicAdd(p + 2, accp.z);
        atomicAdd(p + 3, accp.w);
    }
}

extern "C" void kernel_launch(void* const* d_in, const int* in_sizes, int n_in,
                              void* d_out, int out_size, void* d_ws, size_t ws_size,
                              hipStream_t stream) {
    const int* batch = (const int*)d_in[0];
    const float* x = (const float*)d_in[1];
    const int* edge_index = (const int*)d_in[2];
    const float* edge_attr = (const float*)d_in[3];
    const float* edge_weight = (const float*)d_in[4];
    const float* W_atom = (const float*)d_in[5];
    const float* b_atom = (const float*)d_in[6];
    const float* W_bond = (const float*)d_in[7];
    const float* b_bond = (const float*)d_in[8];
    const float* Wl = (const float*)d_in[9];
    const float* bl = (const float*)d_in[10];
    const float* Wr = (const float*)d_in[11];
    const float* gamma = (const float*)d_in[12];
    const float* beta = (const float*)d_in[13];
    float* out = (float*)d_out;

    // ---- workspace layout ----
    char* ws = (char*)d_ws;
    size_t off = 0;
    auto alloc = [&](size_t bytes) -> void* {
        void* p = ws + off;
        off += (bytes + 255) & ~(size_t)255;
        return p;
    };
    short* Hhi = (short*)alloc((size_t)NNODES * 128 * 2);
    short* Ahi = (short*)alloc((size_t)NNODES * 128 * 2);
    short* Cbf = (short*)alloc((size_t)NNODES * 128 * 2);
    short* Ehi = (short*)alloc((size_t)NNODES * 128 * 2);
    int* epk = (int*)alloc((size_t)NEDGES * 32);
    int2* epg = (int2*)alloc((size_t)NEDGES * 8);
    int* rowptr = (int*)alloc((size_t)(NNODES + 1) * 4);
    int* cursor = (int*)alloc((size_t)NNODES * 4);
    int* deg = (int*)alloc((size_t)NNODES * 4);
    float* stat = (float*)alloc(NLAYERS * 256 * 4);
    int* local_excl = (int*)alloc((size_t)NNODES * 4);
    int* part = (int*)alloc(SCAN_BLOCKS * 4);
    int* blockoff = (int*)alloc(SCAN_BLOCKS * 4);
    short* Bf = (short*)alloc((size_t)NLAYERS * 65536 * 2);

    // ---- preprocessing ----
    init_kernel<<<(NGRAPHS * 640 + 255) / 256, 256, 0, stream>>>(out, deg, stat);
    deg_kernel<<<(NEDGES + 255) / 256, 256, 0, stream>>>(edge_index, deg);
    scan1<<<SCAN_BLOCKS, 256, 0, stream>>>(deg, local_excl, part);
    scan2<<<1, 256, 0, stream>>>(part, blockoff, rowptr);
    scan3<<<SCAN_BLOCKS, 256, 0, stream>>>(local_excl, blockoff, rowptr, cursor);
    edge_fill<<<(NEDGES + 255) / 256, 256, 0, stream>>>(edge_index, edge_weight,
                                                        edge_attr, cursor, epk);
    prep2<<<NSB + EAB + BPB, 256, 0, stream>>>(rowptr, epk, epg, W_bond, b_bond, Ehi,
                                               x, W_atom, b_atom, Hhi, Wl, Wr, Bf);

    // ---- layers ----
    for (int i = 0; i < NLAYERS; i++) {
        agg_kernel<<<(NNODES + 7) / 8, 256, 0, stream>>>(Hhi, Ehi, rowptr, epg, Ahi);
        layer_gemm<<<(NNODES + 127) / 128, 256, 0, stream>>>(Ahi, Hhi,
                                                             Bf + (size_t)i * 65536,
                                                             bl + i * 128, Cbf,
                                                             stat + i * 256);
        int last = (i == NLAYERS - 1);
        bn_apply<<<(NNODES + 255) / 256, 256, 0, stream>>>(
            Cbf, Hhi, last ? (out + (size_t)NGRAPHS * 640) : nullptr,
            stat + i * 256, gamma + i * 128, beta + i * 128, batch, out, i,
            last ? 0 : 1);
    }
}